// Round 7
// baseline (330.997 us; speedup 1.0000x reference)
//
#include <hip/hip_runtime.h>
#include <hip/hip_bf16.h>
#include <math.h>

// Problem constants
#define NB 16          // batch
#define NS 4           // seq (new tokens)
#define NN 2048        // model dim
#define ND 128         // head dim
#define NH 16          // heads
#define NM 4096        // cache length
#define NCHK 8         // M-chunks for split attention
#define CHROWS 512     // rows per chunk (NM/NCHK)
#define TROWS 32       // rows per K/V tile
#define NT 16          // tiles per chunk (CHROWS/TROWS)
#define NKC 16         // k-chunks for QKV split-k

// Workspace layout (float offsets)
#define SC_OFF   0u           // [64] rmsnorm scales
#define Q_OFF    131072u      // [64][2048]
#define K_OFF    262144u      // [64][2048] new K rows
#define V_OFF    393216u      // [64][2048] new V rows
#define OP_OFF   524288u      // [256 bh][8 ch][4 q][128 d] partial O
#define ML_OFF   1572864u     // [256 bh][8 ch][4 q][2] (max, sumexp)
#define PART_OFF 1589248u     // [16 kc][3 which][64][2048] QKV partials (~25MB)

// ------------------------------------------------- RMSNorm scales only
__global__ __launch_bounds__(256) void k_rmsnorm(const float* __restrict__ X,
                                                 float* __restrict__ ws) {
    const int row = blockIdx.x;        // 0..63
    const int tid = threadIdx.x;
    const float* xr = X + (size_t)row * NN;
    float4 a = *(const float4*)(xr + tid * 4);
    float4 b = *(const float4*)(xr + 1024 + tid * 4);
    float ss = a.x*a.x + a.y*a.y + a.z*a.z + a.w*a.w
             + b.x*b.x + b.y*b.y + b.z*b.z + b.w*b.w;
    #pragma unroll
    for (int off = 32; off; off >>= 1) ss += __shfl_xor(ss, off);
    __shared__ float ls[4];
    if ((tid & 63) == 0) ls[tid >> 6] = ss;
    __syncthreads();
    if (tid == 0)
        ws[SC_OFF + row] = rsqrtf((ls[0] + ls[1] + ls[2] + ls[3]) * (1.0f / NN));
}

// -------------------------------------------- QKV projection (tiled f32 GEMM)
// grid (16 col-tiles of 128, 3 which, 16 k-chunks of 128). block 256.
__global__ __launch_bounds__(256) void k_qkv(const float* __restrict__ X,
                                             const float* __restrict__ Wq,
                                             const float* __restrict__ Wk,
                                             const float* __restrict__ Wv,
                                             float* __restrict__ ws) {
    __shared__ float xsT[64][68];    // [kk][row] (+pad)
    __shared__ float wt[64][132];    // [kk][col] (+pad)
    const int ct    = blockIdx.x;    // col tile (128 cols)
    const int which = blockIdx.y;    // 0..2
    const int kc    = blockIdx.z;    // 0..15
    const float* __restrict__ W = (which == 0) ? Wq : (which == 1) ? Wk : Wv;
    const int tid = threadIdx.x;
    const int c0  = ct * 128;
    const int rg  = tid >> 5;        // 0..7 (8 rows each)
    const int cg  = tid & 31;        // 0..31 (4 cols each)
    const float scl = ws[SC_OFF + (tid >> 2)];   // scale for staged row

    float4 acc[8];
    #pragma unroll
    for (int i = 0; i < 8; i++) acc[i] = make_float4(0.f, 0.f, 0.f, 0.f);

    for (int s = 0; s < 2; s++) {
        const int k0 = kc * 128 + s * 64;
        __syncthreads();
        // stage Xn 64x64 transposed (scale applied)
        {
            const int r  = tid >> 2;
            const int q4 = tid & 3;
            #pragma unroll
            for (int i = 0; i < 4; i++) {
                const int f4 = q4 + i * 4;                 // 0..15
                float4 v = *(const float4*)(X + (size_t)r * NN + k0 + f4 * 4);
                xsT[f4 * 4 + 0][r] = v.x * scl;
                xsT[f4 * 4 + 1][r] = v.y * scl;
                xsT[f4 * 4 + 2][r] = v.z * scl;
                xsT[f4 * 4 + 3][r] = v.w * scl;
            }
        }
        // stage W 64x128: per iter 8 rows x 512B contiguous
        {
            #pragma unroll
            for (int j8 = 0; j8 < 8; j8++) {
                const int kk  = j8 * 8 + (tid >> 5);
                const int f4c = tid & 31;
                float4 v = *(const float4*)(W + (size_t)(k0 + kk) * NN + c0 + f4c * 4);
                *(float4*)&wt[kk][f4c * 4] = v;
            }
        }
        __syncthreads();
        #pragma unroll 8
        for (int kk = 0; kk < 64; kk++) {
            const float4 x0 = *(const float4*)&xsT[kk][rg * 8];
            const float4 x1 = *(const float4*)&xsT[kk][rg * 8 + 4];
            const float4 w4 = *(const float4*)&wt[kk][cg * 4];
            acc[0].x += x0.x*w4.x; acc[0].y += x0.x*w4.y; acc[0].z += x0.x*w4.z; acc[0].w += x0.x*w4.w;
            acc[1].x += x0.y*w4.x; acc[1].y += x0.y*w4.y; acc[1].z += x0.y*w4.z; acc[1].w += x0.y*w4.w;
            acc[2].x += x0.z*w4.x; acc[2].y += x0.z*w4.y; acc[2].z += x0.z*w4.z; acc[2].w += x0.z*w4.w;
            acc[3].x += x0.w*w4.x; acc[3].y += x0.w*w4.y; acc[3].z += x0.w*w4.z; acc[3].w += x0.w*w4.w;
            acc[4].x += x1.x*w4.x; acc[4].y += x1.x*w4.y; acc[4].z += x1.x*w4.z; acc[4].w += x1.x*w4.w;
            acc[5].x += x1.y*w4.x; acc[5].y += x1.y*w4.y; acc[5].z += x1.y*w4.z; acc[5].w += x1.y*w4.w;
            acc[6].x += x1.z*w4.x; acc[6].y += x1.z*w4.y; acc[6].z += x1.z*w4.z; acc[6].w += x1.z*w4.w;
            acc[7].x += x1.w*w4.x; acc[7].y += x1.w*w4.y; acc[7].z += x1.w*w4.z; acc[7].w += x1.w*w4.w;
        }
    }
    float* po = ws + PART_OFF + (size_t)(kc * 3 + which) * 131072u;
    #pragma unroll
    for (int i = 0; i < 8; i++)
        *(float4*)(po + (size_t)(rg * 8 + i) * NN + c0 + cg * 4) = acc[i];
}

// ------------------------------------------ sum the 16 k-chunk partials
__global__ __launch_bounds__(256) void k_reduce(float* __restrict__ ws) {
    const int idx = blockIdx.x * 256 + threadIdx.x;    // f4 index, 98304 total
    const int which = idx >> 15;                       // /32768
    const int off   = idx & 32767;                     // f4 within [64][2048]
    float4 s = make_float4(0.f, 0.f, 0.f, 0.f);
    #pragma unroll
    for (int kcc = 0; kcc < NKC; kcc++) {
        const float4 v = *(const float4*)(ws + PART_OFF
                         + (size_t)(kcc * 3 + which) * 131072u + (size_t)off * 4);
        s.x += v.x; s.y += v.y; s.z += v.z; s.w += v.w;
    }
    *(float4*)(ws + Q_OFF + (size_t)which * 131072u + (size_t)off * 4) = s;
}

// ---------------------------------------- split-M flash attention partials
// grid (8 ch, 16 h, 16 b), block 256 = 4 waves. 32-row K/V tiles staged via
// global_load_lds into a TRIPLE buffer (~108KB LDS, 1 block/CU); 2-tile-deep
// prefetch with counted vmcnt(8): the in-flight queue NEVER drains to zero
// in the main loop (loads cross both barriers). K XOR-swizzled both sides.
// Phase A: wave w scores q=w, lane=(half-d, row). Phase B: wave w rows
// [w*8,w*8+8) for all 4 q, V from LDS.
__global__ __launch_bounds__(256) void k_attn(const float* __restrict__ cK,
                                              const float* __restrict__ cV,
                                              const int* __restrict__ Pp,
                                              float* __restrict__ ws) {
    const int ch = blockIdx.x, h = blockIdx.y, b = blockIdx.z;
    const int tid = threadIdx.x;
    const int wv = tid >> 6, lane = tid & 63;
    const int half = lane >> 5, r32 = lane & 31;
    const int P = *Pp;
    __shared__ float Ks[3][TROWS * 128];           // 48KB
    __shared__ float Vs[3][TROWS * 128];           // 48KB
    __shared__ float Qs[4][128] __attribute__((aligned(16)));
    __shared__ float ps[TROWS][4] __attribute__((aligned(16)));
    __shared__ float facs[4] __attribute__((aligned(16)));
    __shared__ float Ow[4][4][128];
    __shared__ float mls[4][2];

    if (tid < 128) {
        const int q = tid >> 5, d = (tid & 31) * 4;
        *(float4*)&Qs[q][d] =
            *(const float4*)(ws + Q_OFF + (size_t)(b * 4 + q) * NN + h * 128 + d);
    }

    const float* kbase = cK + (size_t)(b * NH + h) * NM * ND;
    const float* vbase = cV + (size_t)(b * NH + h) * NM * ND;
    const float* knew  = ws + K_OFF;
    const float* vnew  = ws + V_OFF;
    const int mb0 = ch * CHROWS;

    // stage tile tt (K swizzled + V linear) into buffer bufi; 8 issues/wave
    auto STAGE = [&](int tt, int bufi) {
        const int mb = mb0 + tt * TROWS;
        #pragma unroll
        for (int i = 0; i < 4; i++) {
            const int g0  = (wv * 4 + i) * 64;     // granule group base
            const int g   = g0 + lane;
            const int row = g >> 5;
            const int c4  = g & 31;
            const int csw = c4 ^ (row & 7);
            const int mrow = mb + row;
            const float* src = (mrow >= P && mrow < P + NS)
                ? knew + (size_t)(b * 4 + (mrow - P)) * NN + h * 128 + csw * 4
                : kbase + (size_t)mrow * ND + csw * 4;
            __builtin_amdgcn_global_load_lds(
                (const __attribute__((address_space(1))) void*)src,
                (__attribute__((address_space(3))) void*)(&Ks[bufi][g0 * 4]),
                16, 0, 0);
        }
        #pragma unroll
        for (int i = 0; i < 4; i++) {
            const int g0  = (wv * 4 + i) * 64;
            const int g   = g0 + lane;
            const int row = g >> 5;
            const int c4  = g & 31;
            const int mrow = mb + row;
            const float* src = (mrow >= P && mrow < P + NS)
                ? vnew + (size_t)(b * 4 + (mrow - P)) * NN + h * 128 + c4 * 4
                : vbase + (size_t)mrow * ND + c4 * 4;
            __builtin_amdgcn_global_load_lds(
                (const __attribute__((address_space(1))) void*)src,
                (__attribute__((address_space(3))) void*)(&Vs[bufi][g0 * 4]),
                16, 0, 0);
        }
    };

    float m_run = -INFINITY, l_run = 0.f;
    float2 Oa[4];
    #pragma unroll
    for (int q = 0; q < 4; q++) Oa[q] = make_float2(0.f, 0.f);

    STAGE(0, 0);
    STAGE(1, 1);

    for (int t = 0; t < NT; t++) {
        const int cur = t % 3;
        // tile t confirmed landed; tile t+1's loads remain IN FLIGHT
        if (t < NT - 1)
            asm volatile("s_waitcnt vmcnt(8) lgkmcnt(0)" ::: "memory");
        else
            asm volatile("s_waitcnt vmcnt(0) lgkmcnt(0)" ::: "memory");
        __builtin_amdgcn_s_barrier();
        __builtin_amdgcn_sched_barrier(0);

        // ---- phase A: q=wv; lane computes half-dot for row r32
        const int s7 = r32 & 7;
        const float* kr = &Ks[cur][r32 * 128 + half * 64];
        const float* qr = &Qs[wv][half * 64];
        float s = 0.f;
        #pragma unroll
        for (int j = 0; j < 16; j++) {
            const float4 k4 = *(const float4*)&kr[(j ^ s7) * 4];
            const float4 q4 = *(const float4*)&qr[j * 4];
            s += k4.x*q4.x + k4.y*q4.y + k4.z*q4.z + k4.w*q4.w;
        }
        s += __shfl_xor(s, 32);                    // combine halves
        float wm = s;
        #pragma unroll
        for (int off = 16; off; off >>= 1) wm = fmaxf(wm, __shfl_xor(wm, off));
        const float mn  = fmaxf(m_run, wm);
        const float fac = __expf(m_run - mn);
        m_run = mn;
        const float p = __expf(s - mn);
        l_run = l_run * fac + ((half == 0) ? p : 0.f);
        if (half == 0) ps[r32][wv] = p;
        if (lane == 0) facs[wv] = fac;

        // issue next-next tile: stays in flight across both barriers
        if (t + 2 < NT) STAGE(t + 2, (t + 2) % 3);

        // LDS-only sync; staged global loads stay in flight
        asm volatile("s_waitcnt lgkmcnt(0)" ::: "memory");
        __builtin_amdgcn_s_barrier();
        __builtin_amdgcn_sched_barrier(0);

        // ---- phase B: wave wv rows [wv*8, wv*8+8), V from LDS
        const float4 fq = *(const float4*)&facs[0];
        Oa[0].x *= fq.x; Oa[0].y *= fq.x;
        Oa[1].x *= fq.y; Oa[1].y *= fq.y;
        Oa[2].x *= fq.z; Oa[2].y *= fq.z;
        Oa[3].x *= fq.w; Oa[3].y *= fq.w;
        const int r0 = wv * 8;
        #pragma unroll
        for (int rr = 0; rr < 8; rr++) {
            const float2 v2 = *(const float2*)&Vs[cur][(r0 + rr) * 128 + lane * 2];
            const float4 pr = *(const float4*)&ps[r0 + rr][0];
            Oa[0].x += pr.x * v2.x; Oa[0].y += pr.x * v2.y;
            Oa[1].x += pr.y * v2.x; Oa[1].y += pr.y * v2.y;
            Oa[2].x += pr.z * v2.x; Oa[2].y += pr.z * v2.y;
            Oa[3].x += pr.w * v2.x; Oa[3].y += pr.w * v2.y;
        }
        // no end barrier: next iteration's top barrier fences ps/facs/buffers
    }

    // l sum across lanes (half-1 lanes carry 0 contributions)
    #pragma unroll
    for (int off = 32; off; off >>= 1) l_run += __shfl_xor(l_run, off);
    #pragma unroll
    for (int q = 0; q < 4; q++)
        *(float2*)&Ow[wv][q][lane * 2] = Oa[q];
    if (lane == 0) { mls[wv][0] = m_run; mls[wv][1] = l_run; }
    __syncthreads();

    // block combine: plain sum across waves (same per-q scale sequence)
    const int q = wv;
    const int d0 = lane * 2;
    float o0 = 0.f, o1 = 0.f;
    #pragma unroll
    for (int w2 = 0; w2 < 4; w2++) {
        o0 += Ow[w2][q][d0];
        o1 += Ow[w2][q][d0 + 1];
    }
    const size_t bh = (size_t)(b * NH + h);
    const size_t pidx = ((bh * NCHK + ch) * 4 + q) * 128 + d0;
    ws[OP_OFF + pidx]     = o0;
    ws[OP_OFF + pidx + 1] = o1;
    if (lane == 0) {
        const size_t mi = ((bh * NCHK + ch) * 4 + q) * 2;
        ws[ML_OFF + mi]     = mls[q][0];
        ws[ML_OFF + mi + 1] = mls[q][1];
    }
}

// --------------------------------------------- final combine over chunks
__global__ __launch_bounds__(256) void k_comb(const float* __restrict__ ws,
                                              float* __restrict__ out) {
    const int bh = blockIdx.x;           // 0..255
    const int b = bh >> 4, h = bh & 15;
    const int tid = threadIdx.x;
    const int q = tid >> 6, d0 = (tid & 63) * 2;
    float ms = -INFINITY;
    #pragma unroll
    for (int c = 0; c < NCHK; c++)
        ms = fmaxf(ms, ws[ML_OFF + (((size_t)bh * NCHK + c) * 4 + q) * 2]);
    float o0 = 0.f, o1 = 0.f, den = 0.f;
    #pragma unroll
    for (int c = 0; c < NCHK; c++) {
        const size_t mi = (((size_t)bh * NCHK + c) * 4 + q) * 2;
        float e = __expf(ws[ML_OFF + mi] - ms);
        den += e * ws[ML_OFF + mi + 1];
        const size_t pi = (((size_t)bh * NCHK + c) * 4 + q) * 128 + d0;
        o0 += e * ws[OP_OFF + pi];
        o1 += e * ws[OP_OFF + pi + 1];
    }
    const float inv = 1.0f / den;
    const size_t oi = (size_t)(b * 4 + q) * NN + h * 128 + d0;
    *(float2*)(out + oi) = make_float2(o0 * inv, o1 * inv);
}

// ----------------------------------------------------------------- launch
extern "C" void kernel_launch(void* const* d_in, const int* in_sizes, int n_in,
                              void* d_out, int out_size, void* d_ws, size_t ws_size,
                              hipStream_t stream) {
    const float* X  = (const float*)d_in[0];
    const float* Wq = (const float*)d_in[1];
    const float* Wk = (const float*)d_in[2];
    const float* Wv = (const float*)d_in[3];
    const float* cK = (const float*)d_in[4];
    const float* cV = (const float*)d_in[5];
    const int*   Pp = (const int*)d_in[6];
    float* ws = (float*)d_ws;
    float* out = (float*)d_out;

    hipLaunchKernelGGL(k_rmsnorm, dim3(64), dim3(256), 0, stream, X, ws);
    hipLaunchKernelGGL(k_qkv, dim3(16, 3, NKC), dim3(256), 0, stream, X, Wq, Wk, Wv, ws);
    hipLaunchKernelGGL(k_reduce, dim3(384), dim3(256), 0, stream, ws);
    hipLaunchKernelGGL(k_attn, dim3(NCHK, NH, NB), dim3(256), 0, stream, cK, cV, Pp, ws);
    hipLaunchKernelGGL(k_comb, dim3(NB * NH), dim3(256), 0, stream, ws, out);
}

// Round 8
// 237.633 us; speedup vs baseline: 1.3929x; 1.3929x over previous
//
#include <hip/hip_runtime.h>
#include <hip/hip_bf16.h>
#include <math.h>

// Problem constants
#define NB 16          // batch
#define NS 4           // seq (new tokens)
#define NN 2048        // model dim
#define ND 128         // head dim
#define NH 16          // heads
#define NM 4096        // cache length
#define NCHK 8         // M-chunks for split attention
#define CHROWS 512     // rows per chunk (NM/NCHK)
#define TROWS 32       // rows per K/V tile
#define NT 16          // tiles per chunk (CHROWS/TROWS)
#define NKC 16         // k-chunks for QKV split-k

// Workspace layout (float offsets)
#define SC_OFF   0u           // [64] rmsnorm scales
#define Q_OFF    131072u      // [64][2048]
#define K_OFF    262144u      // [64][2048] new K rows
#define V_OFF    393216u      // [64][2048] new V rows
#define OP_OFF   524288u      // [256 bh][8 ch][4 q][128 d] partial O
#define ML_OFF   1572864u     // [256 bh][8 ch][4 q][2] (max, sumexp)
#define PART_OFF 1589248u     // [16 kc][3 which][64][2048] QKV partials (~25MB)

// ------------------------------------------------- RMSNorm scales only
__global__ __launch_bounds__(256) void k_rmsnorm(const float* __restrict__ X,
                                                 float* __restrict__ ws) {
    const int row = blockIdx.x;        // 0..63
    const int tid = threadIdx.x;
    const float* xr = X + (size_t)row * NN;
    float4 a = *(const float4*)(xr + tid * 4);
    float4 b = *(const float4*)(xr + 1024 + tid * 4);
    float ss = a.x*a.x + a.y*a.y + a.z*a.z + a.w*a.w
             + b.x*b.x + b.y*b.y + b.z*b.z + b.w*b.w;
    #pragma unroll
    for (int off = 32; off; off >>= 1) ss += __shfl_xor(ss, off);
    __shared__ float ls[4];
    if ((tid & 63) == 0) ls[tid >> 6] = ss;
    __syncthreads();
    if (tid == 0)
        ws[SC_OFF + row] = rsqrtf((ls[0] + ls[1] + ls[2] + ls[3]) * (1.0f / NN));
}

// -------------------------------------------- QKV projection (tiled f32 GEMM)
// grid (16 col-tiles of 128, 3 which, 16 k-chunks of 128). block 256.
__global__ __launch_bounds__(256) void k_qkv(const float* __restrict__ X,
                                             const float* __restrict__ Wq,
                                             const float* __restrict__ Wk,
                                             const float* __restrict__ Wv,
                                             float* __restrict__ ws) {
    __shared__ float xsT[64][68];    // [kk][row] (+pad)
    __shared__ float wt[64][132];    // [kk][col] (+pad)
    const int ct    = blockIdx.x;    // col tile (128 cols)
    const int which = blockIdx.y;    // 0..2
    const int kc    = blockIdx.z;    // 0..15
    const float* __restrict__ W = (which == 0) ? Wq : (which == 1) ? Wk : Wv;
    const int tid = threadIdx.x;
    const int c0  = ct * 128;
    const int rg  = tid >> 5;        // 0..7 (8 rows each)
    const int cg  = tid & 31;        // 0..31 (4 cols each)
    const float scl = ws[SC_OFF + (tid >> 2)];   // scale for staged row

    float4 acc[8];
    #pragma unroll
    for (int i = 0; i < 8; i++) acc[i] = make_float4(0.f, 0.f, 0.f, 0.f);

    for (int s = 0; s < 2; s++) {
        const int k0 = kc * 128 + s * 64;
        __syncthreads();
        // stage Xn 64x64 transposed (scale applied)
        {
            const int r  = tid >> 2;
            const int q4 = tid & 3;
            #pragma unroll
            for (int i = 0; i < 4; i++) {
                const int f4 = q4 + i * 4;                 // 0..15
                float4 v = *(const float4*)(X + (size_t)r * NN + k0 + f4 * 4);
                xsT[f4 * 4 + 0][r] = v.x * scl;
                xsT[f4 * 4 + 1][r] = v.y * scl;
                xsT[f4 * 4 + 2][r] = v.z * scl;
                xsT[f4 * 4 + 3][r] = v.w * scl;
            }
        }
        // stage W 64x128: per iter 8 rows x 512B contiguous
        {
            #pragma unroll
            for (int j8 = 0; j8 < 8; j8++) {
                const int kk  = j8 * 8 + (tid >> 5);
                const int f4c = tid & 31;
                float4 v = *(const float4*)(W + (size_t)(k0 + kk) * NN + c0 + f4c * 4);
                *(float4*)&wt[kk][f4c * 4] = v;
            }
        }
        __syncthreads();
        #pragma unroll 8
        for (int kk = 0; kk < 64; kk++) {
            const float4 x0 = *(const float4*)&xsT[kk][rg * 8];
            const float4 x1 = *(const float4*)&xsT[kk][rg * 8 + 4];
            const float4 w4 = *(const float4*)&wt[kk][cg * 4];
            acc[0].x += x0.x*w4.x; acc[0].y += x0.x*w4.y; acc[0].z += x0.x*w4.z; acc[0].w += x0.x*w4.w;
            acc[1].x += x0.y*w4.x; acc[1].y += x0.y*w4.y; acc[1].z += x0.y*w4.z; acc[1].w += x0.y*w4.w;
            acc[2].x += x0.z*w4.x; acc[2].y += x0.z*w4.y; acc[2].z += x0.z*w4.z; acc[2].w += x0.z*w4.w;
            acc[3].x += x0.w*w4.x; acc[3].y += x0.w*w4.y; acc[3].z += x0.w*w4.z; acc[3].w += x0.w*w4.w;
            acc[4].x += x1.x*w4.x; acc[4].y += x1.x*w4.y; acc[4].z += x1.x*w4.z; acc[4].w += x1.x*w4.w;
            acc[5].x += x1.y*w4.x; acc[5].y += x1.y*w4.y; acc[5].z += x1.y*w4.z; acc[5].w += x1.y*w4.w;
            acc[6].x += x1.z*w4.x; acc[6].y += x1.z*w4.y; acc[6].z += x1.z*w4.z; acc[6].w += x1.z*w4.w;
            acc[7].x += x1.w*w4.x; acc[7].y += x1.w*w4.y; acc[7].z += x1.w*w4.z; acc[7].w += x1.w*w4.w;
        }
    }
    float* po = ws + PART_OFF + (size_t)(kc * 3 + which) * 131072u;
    #pragma unroll
    for (int i = 0; i < 8; i++)
        *(float4*)(po + (size_t)(rg * 8 + i) * NN + c0 + cg * 4) = acc[i];
}

// ------------------------------------------ sum the 16 k-chunk partials
__global__ __launch_bounds__(256) void k_reduce(float* __restrict__ ws) {
    const int idx = blockIdx.x * 256 + threadIdx.x;    // f4 index, 98304 total
    const int which = idx >> 15;                       // /32768
    const int off   = idx & 32767;                     // f4 within [64][2048]
    float4 s = make_float4(0.f, 0.f, 0.f, 0.f);
    #pragma unroll
    for (int kcc = 0; kcc < NKC; kcc++) {
        const float4 v = *(const float4*)(ws + PART_OFF
                         + (size_t)(kcc * 3 + which) * 131072u + (size_t)off * 4);
        s.x += v.x; s.y += v.y; s.z += v.z; s.w += v.w;
    }
    *(float4*)(ws + Q_OFF + (size_t)which * 131072u + (size_t)off * 4) = s;
}

// ---------------------------------------- split-M flash attention partials
// grid (8 ch, 16 h, 16 b), block 256 = 4 waves. 32-row K/V tiles staged via
// global_load_lds, DOUBLE-buffered (74.7KB LDS -> 2 blocks/CU) with counted
// vmcnt waits: top wait vmcnt(4) confirms K(t) only; mid wait vmcnt(8)
// confirms V(t) while tile t+1's 8 loads stay in flight across BOTH barriers.
// Per-wave waits sit BEFORE each barrier, so after the barrier all waves'
// granules have landed (no global drain ever). Q held in registers.
__global__ __launch_bounds__(256) void k_attn(const float* __restrict__ cK,
                                              const float* __restrict__ cV,
                                              const int* __restrict__ Pp,
                                              float* __restrict__ ws) {
    const int ch = blockIdx.x, h = blockIdx.y, b = blockIdx.z;
    const int tid = threadIdx.x;
    const int wv = tid >> 6, lane = tid & 63;
    const int half = lane >> 5, r32 = lane & 31;
    const int P = *Pp;
    __shared__ float Ks[2][TROWS * 128];           // 32KB
    __shared__ float Vs[2][TROWS * 128];           // 32KB
    __shared__ float ps[TROWS][4] __attribute__((aligned(16)));
    __shared__ float facs[4] __attribute__((aligned(16)));
    __shared__ float Ow[4][4][128];
    __shared__ float mls[4][2];

    // Q half-row in registers (broadcast within half-group; one-time load)
    const float* qrow = ws + Q_OFF + (size_t)(b * 4 + wv) * NN + h * 128 + half * 64;
    float4 qreg[16];
    #pragma unroll
    for (int j = 0; j < 16; j++) qreg[j] = *(const float4*)(qrow + j * 4);

    const float* kbase = cK + (size_t)(b * NH + h) * NM * ND;
    const float* vbase = cV + (size_t)(b * NH + h) * NM * ND;
    const float* knew  = ws + K_OFF;
    const float* vnew  = ws + V_OFF;
    const int mb0 = ch * CHROWS;

    // stage tile tt (K swizzled, issued FIRST; then V linear) into buffer bufi
    auto STAGE = [&](int tt, int bufi) {
        const int mb = mb0 + tt * TROWS;
        #pragma unroll
        for (int i = 0; i < 4; i++) {
            const int g0  = (wv * 4 + i) * 64;     // granule group base
            const int g   = g0 + lane;
            const int row = g >> 5;
            const int c4  = g & 31;
            const int csw = c4 ^ (row & 7);
            const int mrow = mb + row;
            const float* src = (mrow >= P && mrow < P + NS)
                ? knew + (size_t)(b * 4 + (mrow - P)) * NN + h * 128 + csw * 4
                : kbase + (size_t)mrow * ND + csw * 4;
            __builtin_amdgcn_global_load_lds(
                (const __attribute__((address_space(1))) void*)src,
                (__attribute__((address_space(3))) void*)(&Ks[bufi][g0 * 4]),
                16, 0, 0);
        }
        #pragma unroll
        for (int i = 0; i < 4; i++) {
            const int g0  = (wv * 4 + i) * 64;
            const int g   = g0 + lane;
            const int row = g >> 5;
            const int c4  = g & 31;
            const int mrow = mb + row;
            const float* src = (mrow >= P && mrow < P + NS)
                ? vnew + (size_t)(b * 4 + (mrow - P)) * NN + h * 128 + c4 * 4
                : vbase + (size_t)mrow * ND + c4 * 4;
            __builtin_amdgcn_global_load_lds(
                (const __attribute__((address_space(1))) void*)src,
                (__attribute__((address_space(3))) void*)(&Vs[bufi][g0 * 4]),
                16, 0, 0);
        }
    };

    float m_run = -INFINITY, l_run = 0.f;
    float2 Oa[4];
    #pragma unroll
    for (int q = 0; q < 4; q++) Oa[q] = make_float2(0.f, 0.f);

    STAGE(0, 0);

    for (int t = 0; t < NT; t++) {
        const int cur = t & 1;
        // K(t) landed (this wave's 4 newest = V(t) may still fly);
        // barrier then guarantees ALL waves' K granules landed.
        asm volatile("s_waitcnt vmcnt(4) lgkmcnt(0)" ::: "memory");
        __builtin_amdgcn_s_barrier();
        __builtin_amdgcn_sched_barrier(0);

        // ---- phase A: q=wv; lane computes half-dot for row r32 (K from LDS)
        const int s7 = r32 & 7;
        const float* kr = &Ks[cur][r32 * 128 + half * 64];
        float s = 0.f;
        #pragma unroll
        for (int j = 0; j < 16; j++) {
            const float4 k4 = *(const float4*)&kr[(j ^ s7) * 4];
            const float4 q4 = qreg[j];
            s += k4.x*q4.x + k4.y*q4.y + k4.z*q4.z + k4.w*q4.w;
        }
        s += __shfl_xor(s, 32);                    // combine halves
        float wm = s;
        #pragma unroll
        for (int off = 16; off; off >>= 1) wm = fmaxf(wm, __shfl_xor(wm, off));
        const float mn  = fmaxf(m_run, wm);
        const float fac = __expf(m_run - mn);
        m_run = mn;
        const float p = __expf(s - mn);
        l_run = l_run * fac + ((half == 0) ? p : 0.f);
        if (half == 0) ps[r32][wv] = p;
        if (lane == 0) facs[wv] = fac;

        // issue next tile: its 8 loads stay in flight across both barriers
        if (t + 1 < NT) STAGE(t + 1, cur ^ 1);

        // V(t) landed (8 newest = tile t+1 still flying); ps/facs visible.
        if (t + 1 < NT)
            asm volatile("s_waitcnt vmcnt(8) lgkmcnt(0)" ::: "memory");
        else
            asm volatile("s_waitcnt vmcnt(0) lgkmcnt(0)" ::: "memory");
        __builtin_amdgcn_s_barrier();
        __builtin_amdgcn_sched_barrier(0);

        // ---- phase B: wave wv rows [wv*8, wv*8+8), V from LDS
        const float4 fq = *(const float4*)&facs[0];
        Oa[0].x *= fq.x; Oa[0].y *= fq.x;
        Oa[1].x *= fq.y; Oa[1].y *= fq.y;
        Oa[2].x *= fq.z; Oa[2].y *= fq.z;
        Oa[3].x *= fq.w; Oa[3].y *= fq.w;
        const int r0 = wv * 8;
        #pragma unroll
        for (int rr = 0; rr < 8; rr++) {
            const float2 v2 = *(const float2*)&Vs[cur][(r0 + rr) * 128 + lane * 2];
            const float4 pr = *(const float4*)&ps[r0 + rr][0];
            Oa[0].x += pr.x * v2.x; Oa[0].y += pr.x * v2.y;
            Oa[1].x += pr.y * v2.x; Oa[1].y += pr.y * v2.y;
            Oa[2].x += pr.z * v2.x; Oa[2].y += pr.z * v2.y;
            Oa[3].x += pr.w * v2.x; Oa[3].y += pr.w * v2.y;
        }
        // no end barrier: next iteration's top wait+barrier fences everything
    }

    // l sum across lanes (half-1 lanes carry 0 contributions)
    #pragma unroll
    for (int off = 32; off; off >>= 1) l_run += __shfl_xor(l_run, off);
    #pragma unroll
    for (int q = 0; q < 4; q++)
        *(float2*)&Ow[wv][q][lane * 2] = Oa[q];
    if (lane == 0) { mls[wv][0] = m_run; mls[wv][1] = l_run; }
    __syncthreads();

    // block combine: plain sum across waves (same per-q scale sequence)
    const int q = wv;
    const int d0 = lane * 2;
    float o0 = 0.f, o1 = 0.f;
    #pragma unroll
    for (int w2 = 0; w2 < 4; w2++) {
        o0 += Ow[w2][q][d0];
        o1 += Ow[w2][q][d0 + 1];
    }
    const size_t bh = (size_t)(b * NH + h);
    const size_t pidx = ((bh * NCHK + ch) * 4 + q) * 128 + d0;
    ws[OP_OFF + pidx]     = o0;
    ws[OP_OFF + pidx + 1] = o1;
    if (lane == 0) {
        const size_t mi = ((bh * NCHK + ch) * 4 + q) * 2;
        ws[ML_OFF + mi]     = mls[q][0];
        ws[ML_OFF + mi + 1] = mls[q][1];
    }
}

// --------------------------------------------- final combine over chunks
__global__ __launch_bounds__(256) void k_comb(const float* __restrict__ ws,
                                              float* __restrict__ out) {
    const int bh = blockIdx.x;           // 0..255
    const int b = bh >> 4, h = bh & 15;
    const int tid = threadIdx.x;
    const int q = tid >> 6, d0 = (tid & 63) * 2;
    float ms = -INFINITY;
    #pragma unroll
    for (int c = 0; c < NCHK; c++)
        ms = fmaxf(ms, ws[ML_OFF + (((size_t)bh * NCHK + c) * 4 + q) * 2]);
    float o0 = 0.f, o1 = 0.f, den = 0.f;
    #pragma unroll
    for (int c = 0; c < NCHK; c++) {
        const size_t mi = (((size_t)bh * NCHK + c) * 4 + q) * 2;
        float e = __expf(ws[ML_OFF + mi] - ms);
        den += e * ws[ML_OFF + mi + 1];
        const size_t pi = (((size_t)bh * NCHK + c) * 4 + q) * 128 + d0;
        o0 += e * ws[OP_OFF + pi];
        o1 += e * ws[OP_OFF + pi + 1];
    }
    const float inv = 1.0f / den;
    const size_t oi = (size_t)(b * 4 + q) * NN + h * 128 + d0;
    *(float2*)(out + oi) = make_float2(o0 * inv, o1 * inv);
}

// ----------------------------------------------------------------- launch
extern "C" void kernel_launch(void* const* d_in, const int* in_sizes, int n_in,
                              void* d_out, int out_size, void* d_ws, size_t ws_size,
                              hipStream_t stream) {
    const float* X  = (const float*)d_in[0];
    const float* Wq = (const float*)d_in[1];
    const float* Wk = (const float*)d_in[2];
    const float* Wv = (const float*)d_in[3];
    const float* cK = (const float*)d_in[4];
    const float* cV = (const float*)d_in[5];
    const int*   Pp = (const int*)d_in[6];
    float* ws = (float*)d_ws;
    float* out = (float*)d_out;

    hipLaunchKernelGGL(k_rmsnorm, dim3(64), dim3(256), 0, stream, X, ws);
    hipLaunchKernelGGL(k_qkv, dim3(16, 3, NKC), dim3(256), 0, stream, X, Wq, Wk, Wv, ws);
    hipLaunchKernelGGL(k_reduce, dim3(384), dim3(256), 0, stream, ws);
    hipLaunchKernelGGL(k_attn, dim3(NCHK, NH, NB), dim3(256), 0, stream, cK, cV, Pp, ws);
    hipLaunchKernelGGL(k_comb, dim3(NB * NH), dim3(256), 0, stream, ws, out);
}

// Round 9
// 233.685 us; speedup vs baseline: 1.4164x; 1.0169x over previous
//
#include <hip/hip_runtime.h>
#include <hip/hip_bf16.h>
#include <math.h>

// Problem constants
#define NB 16          // batch
#define NS 4           // seq (new tokens)
#define NN 2048        // model dim
#define ND 128         // head dim
#define NH 16          // heads
#define NM 4096        // cache length
#define NCHK 4         // M-chunks for split attention
#define CHROWS 1024    // rows per chunk (NM/NCHK)
#define TROWS 32       // rows per K/V tile
#define NT 32          // tiles per chunk (CHROWS/TROWS)
#define NKC 16         // k-chunks for QKV split-k

// Workspace layout (float offsets)
#define SC_OFF   0u           // [64] rmsnorm scales
#define Q_OFF    131072u      // [64][2048]
#define K_OFF    262144u      // [64][2048] new K rows
#define V_OFF    393216u      // [64][2048] new V rows
#define OP_OFF   524288u      // [256 bh][ch][4 q][128 d] partial O
#define ML_OFF   1572864u     // [256 bh][ch][4 q][2] (max, sumexp)
#define PART_OFF 1589248u     // [16 kc][3 which][64][2048] QKV partials (~25MB)

// ------------------------------------------------- RMSNorm scales only
__global__ __launch_bounds__(256) void k_rmsnorm(const float* __restrict__ X,
                                                 float* __restrict__ ws) {
    const int row = blockIdx.x;        // 0..63
    const int tid = threadIdx.x;
    const float* xr = X + (size_t)row * NN;
    float4 a = *(const float4*)(xr + tid * 4);
    float4 b = *(const float4*)(xr + 1024 + tid * 4);
    float ss = a.x*a.x + a.y*a.y + a.z*a.z + a.w*a.w
             + b.x*b.x + b.y*b.y + b.z*b.z + b.w*b.w;
    #pragma unroll
    for (int off = 32; off; off >>= 1) ss += __shfl_xor(ss, off);
    __shared__ float ls[4];
    if ((tid & 63) == 0) ls[tid >> 6] = ss;
    __syncthreads();
    if (tid == 0)
        ws[SC_OFF + row] = rsqrtf((ls[0] + ls[1] + ls[2] + ls[3]) * (1.0f / NN));
}

// -------------------------------------------- QKV projection (tiled f32 GEMM)
// grid (16 col-tiles of 128, 3 which, 16 k-chunks of 128). block 256.
__global__ __launch_bounds__(256) void k_qkv(const float* __restrict__ X,
                                             const float* __restrict__ Wq,
                                             const float* __restrict__ Wk,
                                             const float* __restrict__ Wv,
                                             float* __restrict__ ws) {
    __shared__ float xsT[64][68];    // [kk][row] (+pad)
    __shared__ float wt[64][132];    // [kk][col] (+pad)
    const int ct    = blockIdx.x;    // col tile (128 cols)
    const int which = blockIdx.y;    // 0..2
    const int kc    = blockIdx.z;    // 0..15
    const float* __restrict__ W = (which == 0) ? Wq : (which == 1) ? Wk : Wv;
    const int tid = threadIdx.x;
    const int c0  = ct * 128;
    const int rg  = tid >> 5;        // 0..7 (8 rows each)
    const int cg  = tid & 31;        // 0..31 (4 cols each)
    const float scl = ws[SC_OFF + (tid >> 2)];   // scale for staged row

    float4 acc[8];
    #pragma unroll
    for (int i = 0; i < 8; i++) acc[i] = make_float4(0.f, 0.f, 0.f, 0.f);

    for (int s = 0; s < 2; s++) {
        const int k0 = kc * 128 + s * 64;
        __syncthreads();
        // stage Xn 64x64 transposed (scale applied)
        {
            const int r  = tid >> 2;
            const int q4 = tid & 3;
            #pragma unroll
            for (int i = 0; i < 4; i++) {
                const int f4 = q4 + i * 4;                 // 0..15
                float4 v = *(const float4*)(X + (size_t)r * NN + k0 + f4 * 4);
                xsT[f4 * 4 + 0][r] = v.x * scl;
                xsT[f4 * 4 + 1][r] = v.y * scl;
                xsT[f4 * 4 + 2][r] = v.z * scl;
                xsT[f4 * 4 + 3][r] = v.w * scl;
            }
        }
        // stage W 64x128: per iter 8 rows x 512B contiguous
        {
            #pragma unroll
            for (int j8 = 0; j8 < 8; j8++) {
                const int kk  = j8 * 8 + (tid >> 5);
                const int f4c = tid & 31;
                float4 v = *(const float4*)(W + (size_t)(k0 + kk) * NN + c0 + f4c * 4);
                *(float4*)&wt[kk][f4c * 4] = v;
            }
        }
        __syncthreads();
        #pragma unroll 8
        for (int kk = 0; kk < 64; kk++) {
            const float4 x0 = *(const float4*)&xsT[kk][rg * 8];
            const float4 x1 = *(const float4*)&xsT[kk][rg * 8 + 4];
            const float4 w4 = *(const float4*)&wt[kk][cg * 4];
            acc[0].x += x0.x*w4.x; acc[0].y += x0.x*w4.y; acc[0].z += x0.x*w4.z; acc[0].w += x0.x*w4.w;
            acc[1].x += x0.y*w4.x; acc[1].y += x0.y*w4.y; acc[1].z += x0.y*w4.z; acc[1].w += x0.y*w4.w;
            acc[2].x += x0.z*w4.x; acc[2].y += x0.z*w4.y; acc[2].z += x0.z*w4.z; acc[2].w += x0.z*w4.w;
            acc[3].x += x0.w*w4.x; acc[3].y += x0.w*w4.y; acc[3].z += x0.w*w4.z; acc[3].w += x0.w*w4.w;
            acc[4].x += x1.x*w4.x; acc[4].y += x1.x*w4.y; acc[4].z += x1.x*w4.z; acc[4].w += x1.x*w4.w;
            acc[5].x += x1.y*w4.x; acc[5].y += x1.y*w4.y; acc[5].z += x1.y*w4.z; acc[5].w += x1.y*w4.w;
            acc[6].x += x1.z*w4.x; acc[6].y += x1.z*w4.y; acc[6].z += x1.z*w4.z; acc[6].w += x1.z*w4.w;
            acc[7].x += x1.w*w4.x; acc[7].y += x1.w*w4.y; acc[7].z += x1.w*w4.z; acc[7].w += x1.w*w4.w;
        }
    }
    float* po = ws + PART_OFF + (size_t)(kc * 3 + which) * 131072u;
    #pragma unroll
    for (int i = 0; i < 8; i++)
        *(float4*)(po + (size_t)(rg * 8 + i) * NN + c0 + cg * 4) = acc[i];
}

// ------------------------------------------ sum the 16 k-chunk partials
__global__ __launch_bounds__(256) void k_reduce(float* __restrict__ ws) {
    const int idx = blockIdx.x * 256 + threadIdx.x;    // f4 index, 98304 total
    const int which = idx >> 15;                       // /32768
    const int off   = idx & 32767;                     // f4 within [64][2048]
    float4 s = make_float4(0.f, 0.f, 0.f, 0.f);
    #pragma unroll
    for (int kcc = 0; kcc < NKC; kcc++) {
        const float4 v = *(const float4*)(ws + PART_OFF
                         + (size_t)(kcc * 3 + which) * 131072u + (size_t)off * 4);
        s.x += v.x; s.y += v.y; s.z += v.z; s.w += v.w;
    }
    *(float4*)(ws + Q_OFF + (size_t)which * 131072u + (size_t)off * 4) = s;
}

// ---------------------------------------- split-M flash attention partials
// grid (4 ch, 16 h, 16 b) = 1024 blocks, block 256 = 4 waves; 2 blocks/CU =
// exactly 2 occupancy rounds. 32-row K/V tiles via global_load_lds, double-
// buffered. WAVE-CONTIGUOUS STREAMS: wave0 stages K rows 0-15 (8KB contig),
// wave1 K rows 16-31, wave2 V rows 0-15, wave3 V rows 16-31 — one stream per
// wave instead of interleaved 4KB K/V bursts (DRAM-locality experiment).
// K XOR-swizzled both sides; V linear. Q in registers.
__global__ __launch_bounds__(256) void k_attn(const float* __restrict__ cK,
                                              const float* __restrict__ cV,
                                              const int* __restrict__ Pp,
                                              float* __restrict__ ws) {
    const int ch = blockIdx.x, h = blockIdx.y, b = blockIdx.z;
    const int tid = threadIdx.x;
    const int wv = tid >> 6, lane = tid & 63;
    const int half = lane >> 5, r32 = lane & 31;
    const int P = *Pp;
    __shared__ float Ks[2][TROWS * 128];           // 32KB
    __shared__ float Vs[2][TROWS * 128];           // 32KB
    __shared__ float ps[TROWS][4] __attribute__((aligned(16)));
    __shared__ float facs[4] __attribute__((aligned(16)));
    __shared__ float Ow[4][4][128];
    __shared__ float mls[4][2];

    // Q half-row in registers (broadcast within half-group; one-time load)
    const float* qrow = ws + Q_OFF + (size_t)(b * 4 + wv) * NN + h * 128 + half * 64;
    float4 qreg[16];
    #pragma unroll
    for (int j = 0; j < 16; j++) qreg[j] = *(const float4*)(qrow + j * 4);

    const float* kbase = cK + (size_t)(b * NH + h) * NM * ND;
    const float* vbase = cV + (size_t)(b * NH + h) * NM * ND;
    const float* knew  = ws + K_OFF;
    const float* vnew  = ws + V_OFF;
    const int mb0 = ch * CHROWS;

    // stage tile tt into buffer bufi; 8 issues/wave, one contiguous 8KB
    // stream per wave. Granule->LDS mapping identical to previous rounds.
    auto STAGE = [&](int tt, int bufi) {
        const int mb = mb0 + tt * TROWS;
        if (wv < 2) {
            #pragma unroll
            for (int i = 0; i < 8; i++) {
                const int g0  = (wv * 8 + i) * 64;     // granule group base
                const int g   = g0 + lane;
                const int row = g >> 5;
                const int c4  = g & 31;
                const int csw = c4 ^ (row & 7);
                const int mrow = mb + row;
                const float* src = (mrow >= P && mrow < P + NS)
                    ? knew + (size_t)(b * 4 + (mrow - P)) * NN + h * 128 + csw * 4
                    : kbase + (size_t)mrow * ND + csw * 4;
                __builtin_amdgcn_global_load_lds(
                    (const __attribute__((address_space(1))) void*)src,
                    (__attribute__((address_space(3))) void*)(&Ks[bufi][g0 * 4]),
                    16, 0, 0);
            }
        } else {
            #pragma unroll
            for (int i = 0; i < 8; i++) {
                const int g0  = ((wv - 2) * 8 + i) * 64;
                const int g   = g0 + lane;
                const int row = g >> 5;
                const int c4  = g & 31;
                const int mrow = mb + row;
                const float* src = (mrow >= P && mrow < P + NS)
                    ? vnew + (size_t)(b * 4 + (mrow - P)) * NN + h * 128 + c4 * 4
                    : vbase + (size_t)mrow * ND + c4 * 4;
                __builtin_amdgcn_global_load_lds(
                    (const __attribute__((address_space(1))) void*)src,
                    (__attribute__((address_space(3))) void*)(&Vs[bufi][g0 * 4]),
                    16, 0, 0);
            }
        }
    };

    float m_run = -INFINITY, l_run = 0.f;
    float2 Oa[4];
    #pragma unroll
    for (int q = 0; q < 4; q++) Oa[q] = make_float2(0.f, 0.f);

    STAGE(0, 0);

    for (int t = 0; t < NT; t++) {
        const int cur = t & 1;
        // tile t fully landed (per-wave), then block-wide barrier
        asm volatile("s_waitcnt vmcnt(0) lgkmcnt(0)" ::: "memory");
        __builtin_amdgcn_s_barrier();
        __builtin_amdgcn_sched_barrier(0);

        // issue next tile immediately (hazard-free: all waves passed barrier)
        if (t + 1 < NT) STAGE(t + 1, cur ^ 1);

        // ---- phase A: q=wv; lane computes half-dot for row r32 (K from LDS)
        const int s7 = r32 & 7;
        const float* kr = &Ks[cur][r32 * 128 + half * 64];
        float s = 0.f;
        #pragma unroll
        for (int j = 0; j < 16; j++) {
            const float4 k4 = *(const float4*)&kr[(j ^ s7) * 4];
            const float4 q4 = qreg[j];
            s += k4.x*q4.x + k4.y*q4.y + k4.z*q4.z + k4.w*q4.w;
        }
        s += __shfl_xor(s, 32);                    // combine halves
        float wm = s;
        #pragma unroll
        for (int off = 16; off; off >>= 1) wm = fmaxf(wm, __shfl_xor(wm, off));
        const float mn  = fmaxf(m_run, wm);
        const float fac = __expf(m_run - mn);
        m_run = mn;
        const float p = __expf(s - mn);
        l_run = l_run * fac + ((half == 0) ? p : 0.f);
        if (half == 0) ps[r32][wv] = p;
        if (lane == 0) facs[wv] = fac;

        // LDS-only sync; next tile's staged loads stay in flight
        asm volatile("s_waitcnt lgkmcnt(0)" ::: "memory");
        __builtin_amdgcn_s_barrier();
        __builtin_amdgcn_sched_barrier(0);

        // ---- phase B: wave wv rows [wv*8, wv*8+8), V from LDS
        const float4 fq = *(const float4*)&facs[0];
        Oa[0].x *= fq.x; Oa[0].y *= fq.x;
        Oa[1].x *= fq.y; Oa[1].y *= fq.y;
        Oa[2].x *= fq.z; Oa[2].y *= fq.z;
        Oa[3].x *= fq.w; Oa[3].y *= fq.w;
        const int r0 = wv * 8;
        #pragma unroll
        for (int rr = 0; rr < 8; rr++) {
            const float2 v2 = *(const float2*)&Vs[cur][(r0 + rr) * 128 + lane * 2];
            const float4 pr = *(const float4*)&ps[r0 + rr][0];
            Oa[0].x += pr.x * v2.x; Oa[0].y += pr.x * v2.y;
            Oa[1].x += pr.y * v2.x; Oa[1].y += pr.y * v2.y;
            Oa[2].x += pr.z * v2.x; Oa[2].y += pr.z * v2.y;
            Oa[3].x += pr.w * v2.x; Oa[3].y += pr.w * v2.y;
        }
        // no end barrier: next iteration's top wait+barrier fences everything
    }

    // l sum across lanes (half-1 lanes carry 0 contributions)
    #pragma unroll
    for (int off = 32; off; off >>= 1) l_run += __shfl_xor(l_run, off);
    #pragma unroll
    for (int q = 0; q < 4; q++)
        *(float2*)&Ow[wv][q][lane * 2] = Oa[q];
    if (lane == 0) { mls[wv][0] = m_run; mls[wv][1] = l_run; }
    __syncthreads();

    // block combine: plain sum across waves (same per-q scale sequence)
    const int q = wv;
    const int d0 = lane * 2;
    float o0 = 0.f, o1 = 0.f;
    #pragma unroll
    for (int w2 = 0; w2 < 4; w2++) {
        o0 += Ow[w2][q][d0];
        o1 += Ow[w2][q][d0 + 1];
    }
    const size_t bh = (size_t)(b * NH + h);
    const size_t pidx = ((bh * NCHK + ch) * 4 + q) * 128 + d0;
    ws[OP_OFF + pidx]     = o0;
    ws[OP_OFF + pidx + 1] = o1;
    if (lane == 0) {
        const size_t mi = ((bh * NCHK + ch) * 4 + q) * 2;
        ws[ML_OFF + mi]     = mls[q][0];
        ws[ML_OFF + mi + 1] = mls[q][1];
    }
}

// --------------------------------------------- final combine over chunks
__global__ __launch_bounds__(256) void k_comb(const float* __restrict__ ws,
                                              float* __restrict__ out) {
    const int bh = blockIdx.x;           // 0..255
    const int b = bh >> 4, h = bh & 15;
    const int tid = threadIdx.x;
    const int q = tid >> 6, d0 = (tid & 63) * 2;
    float ms = -INFINITY;
    #pragma unroll
    for (int c = 0; c < NCHK; c++)
        ms = fmaxf(ms, ws[ML_OFF + (((size_t)bh * NCHK + c) * 4 + q) * 2]);
    float o0 = 0.f, o1 = 0.f, den = 0.f;
    #pragma unroll
    for (int c = 0; c < NCHK; c++) {
        const size_t mi = (((size_t)bh * NCHK + c) * 4 + q) * 2;
        float e = __expf(ws[ML_OFF + mi] - ms);
        den += e * ws[ML_OFF + mi + 1];
        const size_t pi = (((size_t)bh * NCHK + c) * 4 + q) * 128 + d0;
        o0 += e * ws[OP_OFF + pi];
        o1 += e * ws[OP_OFF + pi + 1];
    }
    const float inv = 1.0f / den;
    const size_t oi = (size_t)(b * 4 + q) * NN + h * 128 + d0;
    *(float2*)(out + oi) = make_float2(o0 * inv, o1 * inv);
}

// ----------------------------------------------------------------- launch
extern "C" void kernel_launch(void* const* d_in, const int* in_sizes, int n_in,
                              void* d_out, int out_size, void* d_ws, size_t ws_size,
                              hipStream_t stream) {
    const float* X  = (const float*)d_in[0];
    const float* Wq = (const float*)d_in[1];
    const float* Wk = (const float*)d_in[2];
    const float* Wv = (const float*)d_in[3];
    const float* cK = (const float*)d_in[4];
    const float* cV = (const float*)d_in[5];
    const int*   Pp = (const int*)d_in[6];
    float* ws = (float*)d_ws;
    float* out = (float*)d_out;

    hipLaunchKernelGGL(k_rmsnorm, dim3(64), dim3(256), 0, stream, X, ws);
    hipLaunchKernelGGL(k_qkv, dim3(16, 3, NKC), dim3(256), 0, stream, X, Wq, Wk, Wv, ws);
    hipLaunchKernelGGL(k_reduce, dim3(384), dim3(256), 0, stream, ws);
    hipLaunchKernelGGL(k_attn, dim3(NCHK, NH, NB), dim3(256), 0, stream, cK, cV, Pp, ws);
    hipLaunchKernelGGL(k_comb, dim3(NB * NH), dim3(256), 0, stream, ws, out);
}